// Round 3
// baseline (364.411 us; speedup 1.0000x reference)
//
#include <hip/hip_runtime.h>

// Problem dims
#define NN 128
#define MM 2048
#define EPSF 0.01f

typedef __bf16 bf16x8 __attribute__((ext_vector_type(8)));
typedef __bf16 bf16x4 __attribute__((ext_vector_type(4)));
typedef float  f32x4  __attribute__((ext_vector_type(4)));

// Workspace layout (float offsets), total 494720 floats = 1.98 MB
#define WS_SLACK 0            // [n][m] fp32
#define WS_W2    262144       // [n][256] gz2*softplus(Wz2)
#define WS_GZ1   294912       // [n][256]
#define WS_YV    327680       // [n][8]  Y - gy2*Wy2
#define WS_CU2   328704       // [n]
#define WS_U1    328832       // [n][256] fp32
#define WS_U2    361600       // [n][256]
#define WS_C0    394368       // [n][256]
#define WS_C1    427136       // [n][256]
#define WS_GY0   459904       // [n][8]
#define WS_GY1   460928       // [n][8]
#define WS_WTB   461952       // bf16 [256 k][256 z] = softplus(Wz1)

__device__ __forceinline__ float softplusf(float x) {
    return x > 20.f ? x : log1pf(expf(x));
}

__device__ __forceinline__ bf16x8 ld_cvt8(const float* __restrict__ p) {
    const float4* p4 = (const float4*)p;
    float4 a = p4[0], b = p4[1];
    bf16x8 r;
    r[0] = (__bf16)a.x; r[1] = (__bf16)a.y; r[2] = (__bf16)a.z; r[3] = (__bf16)a.w;
    r[4] = (__bf16)b.x; r[5] = (__bf16)b.y; r[6] = (__bf16)b.z; r[7] = (__bf16)b.w;
    return r;
}

// ---------------------------------------------------------------------------
// k_prep: WTB[k*256+z] = bf16(softplus(Wz1[k][z]))
// ---------------------------------------------------------------------------
__global__ __launch_bounds__(256) void k_prep(const float* __restrict__ Wz1,
                                              float* __restrict__ ws) {
    int i = blockIdx.x * 256 + threadIdx.x;   // 65536
    ((__bf16*)(ws + WS_WTB))[i] = (__bf16)softplusf(Wz1[i]);
}

// ---------------------------------------------------------------------------
// Batched context-path GEMM levels: M=128 rows (n), bf16 MFMA, fp32 I/O.
// Each block: 4 waves x 16 output cols; D[m][k]: col=c (k), row=16mi+4q+r (m).
// ---------------------------------------------------------------------------
#define LVL_GEMM(KDIM, APTR)                                                   \
    f32x4 D[8];                                                                \
    _Pragma("unroll")                                                          \
    for (int mi = 0; mi < 8; ++mi) D[mi] = f32x4{0.f, 0.f, 0.f, 0.f};          \
    _Pragma("unroll")                                                          \
    for (int ch = 0; ch < (KDIM) / 32; ++ch) {                                 \
        bf16x8 bF = ld_cvt8(Wsrc + ch * 32 + q * 8);                           \
        _Pragma("unroll")                                                      \
        for (int j = 0; j < 8; ++j) bF[j] = kv ? bF[j] : (__bf16)0.f;          \
        _Pragma("unroll")                                                      \
        for (int mi = 0; mi < 8; ++mi) {                                       \
            bf16x8 aF = ld_cvt8((APTR) + (c + 16 * mi) * (KDIM) + ch * 32 + q * 8); \
            D[mi] = __builtin_amdgcn_mfma_f32_16x16x32_bf16(aF, bF, D[mi], 0, 0, 0); \
        }                                                                      \
    }

__global__ __launch_bounds__(256) void k_lvlA(
    const float* __restrict__ X,
    const float* __restrict__ Wt0, const float* __restrict__ bt0,
    const float* __restrict__ Wu0, const float* __restrict__ b0,
    const float* __restrict__ Wyu0, const float* __restrict__ byu0,
    float* __restrict__ ws)
{
    const int t = threadIdx.x, w = t >> 6, lane = t & 63;
    const int c = lane & 15, q = lane >> 4, b = blockIdx.x;
    const float* W; const float* bias; int mode, colbase;
    if (b < 4)      { W = Wt0;  bias = bt0;  mode = 0; colbase = b * 64; }
    else if (b < 8) { W = Wu0;  bias = b0;   mode = 1; colbase = (b - 4) * 64; }
    else            { W = Wyu0; bias = byu0; mode = 2; colbase = 0; }
    if (mode == 2 && w > 0) return;
    const int k = colbase + 16 * w + c;
    const bool kv = (mode < 2) || (k < 8);
    const float* Wsrc = W + (kv ? k : 0) * 64;

    LVL_GEMM(64, X)

    if (!kv) return;
    float bv = bias[k];
#pragma unroll
    for (int mi = 0; mi < 8; ++mi)
#pragma unroll
        for (int r = 0; r < 4; ++r) {
            int m = 16 * mi + 4 * q + r;
            float val = D[mi][r] + bv;
            if (mode == 0)      ws[WS_U1 + m * 256 + k] = fmaxf(val, 0.f);
            else if (mode == 1) ws[WS_C0 + m * 256 + k] = val;
            else                ws[WS_GY0 + m * 8 + k] = val;
        }
}

__global__ __launch_bounds__(256) void k_lvlB(
    const float* __restrict__ Wt1, const float* __restrict__ bt1,
    const float* __restrict__ Wzu1, const float* __restrict__ bzu1,
    const float* __restrict__ Wu1, const float* __restrict__ b1,
    const float* __restrict__ Wyu1, const float* __restrict__ byu1,
    float* __restrict__ ws)
{
    const int t = threadIdx.x, w = t >> 6, lane = t & 63;
    const int c = lane & 15, q = lane >> 4, b = blockIdx.x;
    const float* W; const float* bias; int mode, colbase;
    if (b < 4)       { W = Wt1;  bias = bt1;  mode = 0; colbase = b * 64; }
    else if (b < 8)  { W = Wzu1; bias = bzu1; mode = 1; colbase = (b - 4) * 64; }
    else if (b < 12) { W = Wu1;  bias = b1;   mode = 2; colbase = (b - 8) * 64; }
    else             { W = Wyu1; bias = byu1; mode = 3; colbase = 0; }
    if (mode == 3 && w > 0) return;
    const int k = colbase + 16 * w + c;
    const bool kv = (mode < 3) || (k < 8);
    const float* Wsrc = W + (kv ? k : 0) * 256;
    const float* A = ws + WS_U1;

    LVL_GEMM(256, A)

    if (!kv) return;
    float bv = bias[k];
#pragma unroll
    for (int mi = 0; mi < 8; ++mi)
#pragma unroll
        for (int r = 0; r < 4; ++r) {
            int m = 16 * mi + 4 * q + r;
            float val = D[mi][r] + bv;
            if (mode == 0)      ws[WS_U2 + m * 256 + k] = fmaxf(val, 0.f);
            else if (mode == 1) ws[WS_GZ1 + m * 256 + k] = fmaxf(val, 0.f);
            else if (mode == 2) ws[WS_C1 + m * 256 + k] = val;
            else                ws[WS_GY1 + m * 8 + k] = val;
        }
}

__global__ __launch_bounds__(256) void k_lvlC(
    const float* __restrict__ Y,
    const float* __restrict__ Wzu2, const float* __restrict__ bzu2,
    const float* __restrict__ Wz2,
    const float* __restrict__ Wyu2, const float* __restrict__ byu2,
    const float* __restrict__ Wy2,
    const float* __restrict__ Wu2, const float* __restrict__ b2,
    float* __restrict__ ws)
{
    const int t = threadIdx.x, w = t >> 6, lane = t & 63;
    const int c = lane & 15, q = lane >> 4, b = blockIdx.x;
    int mode = (b < 4) ? 0 : 1;
    if (mode == 1 && w > 0) return;
    const int k = (mode == 0) ? (b * 64 + 16 * w + c) : c;
    const bool kv = (mode == 0) || (k <= 8);
    const float* Wsrc;
    if (mode == 0) Wsrc = Wzu2 + k * 256;
    else           Wsrc = (k < 8) ? (Wyu2 + k * 256) : Wu2;   // k==8 -> Wu2; k>8 masked
    const float* A = ws + WS_U2;

    LVL_GEMM(256, A)

    if (!kv) return;
#pragma unroll
    for (int mi = 0; mi < 8; ++mi)
#pragma unroll
        for (int r = 0; r < 4; ++r) {
            int m = 16 * mi + 4 * q + r;
            if (mode == 0) {
                float gz2 = fmaxf(D[mi][r] + bzu2[k], 0.f);
                ws[WS_W2 + m * 256 + k] = gz2 * softplusf(Wz2[k]);
            } else if (k < 8) {
                float gy2 = D[mi][r] + byu2[k];
                ws[WS_YV + m * 8 + k] = Y[m * 8 + k] - gy2 * Wy2[k];
            } else {  // k == 8
                ws[WS_CU2 + m] = D[mi][r] + b2[0];
            }
        }
}

// ---------------------------------------------------------------------------
// k_main: per (m-pair, n): WTb fragments register-resident; loop s over two
// 64-m subtiles: pre-GEMM (zh, XOR-swizzled LDS), 8-chunk main GEMM + rank-1
// chunk, fused epilogue -> slack.
// ---------------------------------------------------------------------------
__device__ __forceinline__ int zh_off(int m, int ci) {   // ci = 16B-chunk idx (8 bf16)
    return m * 256 + ((ci ^ (m & 7)) << 3);
}

__global__ __launch_bounds__(256, 2) void k_main(
    const float* __restrict__ U,
    const float* __restrict__ Wy0,
    const float* __restrict__ Wy1,
    float* __restrict__ ws)
{
    __shared__ __bf16 zh[64 * 256];    // 32 KB, XOR-swizzled
    __shared__ float gz1s[256];
    __shared__ float w2s[256];
    __shared__ float c0s[256];
    __shared__ float c1s[256];
    __shared__ float gy0s[8], gy1s[8];
    __shared__ float psum[4][64];

    const int t = threadIdx.x;
    const int n = blockIdx.y;
    const int mp = blockIdx.x;
    const int w = t >> 6, lane = t & 63;
    const int c = lane & 15, q = lane >> 4;

    gz1s[t] = ws[WS_GZ1 + n * 256 + t];
    w2s[t]  = ws[WS_W2  + n * 256 + t];
    c0s[t]  = ws[WS_C0  + n * 256 + t];
    c1s[t]  = ws[WS_C1  + n * 256 + t];
    if (t < 8) { gy0s[t] = ws[WS_GY0 + n * 8 + t]; gy1s[t] = ws[WS_GY1 + n * 8 + t]; }
    const float cu2 = ws[WS_CU2 + n];

    // register-resident softplus(Wz1) fragments: wave w covers k in [64w,64w+64)
    const __bf16* WTp = (const __bf16*)(ws + WS_WTB);
    bf16x8 bwr[8][4];
#pragma unroll
    for (int ch = 0; ch < 8; ++ch)
#pragma unroll
        for (int kj = 0; kj < 4; ++kj)
            bwr[ch][kj] = *(const bf16x8*)(WTp + (64 * w + 16 * kj + c) * 256 + ch * 32 + q * 8);

    __syncthreads();   // staging visible

#pragma unroll 1
    for (int s = 0; s < 2; ++s) {
        const int m0 = mp * 128 + s * 64;

        // A2 frags: [U | 1 | 0...] rows m = m0 + c + 16mi
        bf16x8 a2f[4];
#pragma unroll
        for (int mi = 0; mi < 4; ++mi) {
            const float4* up = (const float4*)(U + (m0 + c + 16 * mi) * 8);
            float4 u0 = up[0], u1 = up[1];
            float uv[8] = {u0.x, u0.y, u0.z, u0.w, u1.x, u1.y, u1.z, u1.w};
#pragma unroll
            for (int j = 0; j < 8; ++j) {
                float val = (q == 0) ? uv[j] : ((q == 1 && j == 0) ? 1.f : 0.f);
                a2f[mi][j] = (__bf16)val;
            }
        }

        // ---- pre-GEMM: zh[m][z] = relu(B2[z]·A2[m]) * gz1[z] ----
#pragma unroll
        for (int zt = 0; zt < 4; ++zt) {
            const int z = 64 * w + 16 * zt + c;
            const float4* wy = (const float4*)(Wy0 + z * 8);
            float4 wa = wy[0], wb = wy[1];
            float wv[8] = {wa.x, wa.y, wa.z, wa.w, wb.x, wb.y, wb.z, wb.w};
            const float c0v = c0s[z];
            bf16x8 b2f;
#pragma unroll
            for (int j = 0; j < 8; ++j) {
                float val = (q == 0) ? gy0s[j] * wv[j] : ((q == 1 && j == 0) ? c0v : 0.f);
                b2f[j] = (__bf16)val;
            }
            f32x4 pr[4];
#pragma unroll
            for (int mi = 0; mi < 4; ++mi) {
                f32x4 zacc = {0.f, 0.f, 0.f, 0.f};
                pr[mi] = __builtin_amdgcn_mfma_f32_16x16x32_bf16(b2f, a2f[mi], zacc, 0, 0, 0);
            }
            const int zb = 64 * w + 16 * zt + 4 * q;
#pragma unroll
            for (int mi = 0; mi < 4; ++mi) {
                bf16x4 v4;
#pragma unroll
                for (int r = 0; r < 4; ++r)
                    v4[r] = (__bf16)(fmaxf(pr[mi][r], 0.f) * gz1s[zb + r]);
                *(bf16x4*)&zh[zh_off(c + 16 * mi, zb >> 3) + (zb & 7)] = v4;
            }
        }
        __syncthreads();   // zh ready (also guards psum reuse across s)

        // ---- main GEMM: acc[m][k] over 8 z-chunks ----
        f32x4 acc[4][4];
#pragma unroll
        for (int mi = 0; mi < 4; ++mi)
#pragma unroll
            for (int kj = 0; kj < 4; ++kj)
                acc[mi][kj] = f32x4{0.f, 0.f, 0.f, 0.f};

#pragma unroll
        for (int ch = 0; ch < 8; ++ch) {
            bf16x8 az[4];
#pragma unroll
            for (int mi = 0; mi < 4; ++mi)
                az[mi] = *(const bf16x8*)&zh[zh_off(c + 16 * mi, ch * 4 + q)];
#pragma unroll
            for (int mi = 0; mi < 4; ++mi)
#pragma unroll
                for (int kj = 0; kj < 4; ++kj)
                    acc[mi][kj] = __builtin_amdgcn_mfma_f32_16x16x32_bf16(
                        az[mi], bwr[ch][kj], acc[mi][kj], 0, 0, 0);
        }
        // rank-1 chunk: [U|1] x [gy1*Wy1 | c1]
#pragma unroll
        for (int kj = 0; kj < 4; ++kj) {
            const int k = 64 * w + 16 * kj + c;
            const float4* wy = (const float4*)(Wy1 + k * 8);
            float4 wa = wy[0], wb = wy[1];
            float wv[8] = {wa.x, wa.y, wa.z, wa.w, wb.x, wb.y, wb.z, wb.w};
            const float c1v = c1s[k];
            bf16x8 bx;
#pragma unroll
            for (int j = 0; j < 8; ++j) {
                float val = (q == 0) ? gy1s[j] * wv[j] : ((q == 1 && j == 0) ? c1v : 0.f);
                bx[j] = (__bf16)val;
            }
#pragma unroll
            for (int mi = 0; mi < 4; ++mi)
                acc[mi][kj] = __builtin_amdgcn_mfma_f32_16x16x32_bf16(
                    a2f[mi], bx, acc[mi][kj], 0, 0, 0);
        }

        // ---- epilogue: p[m] = sum_k relu(acc)*w2[k] ----
        float p[4][4];
#pragma unroll
        for (int mi = 0; mi < 4; ++mi)
#pragma unroll
            for (int r = 0; r < 4; ++r) p[mi][r] = 0.f;
#pragma unroll
        for (int kj = 0; kj < 4; ++kj) {
            const float w2v = w2s[64 * w + 16 * kj + c];
#pragma unroll
            for (int mi = 0; mi < 4; ++mi)
#pragma unroll
                for (int r = 0; r < 4; ++r)
                    p[mi][r] += fmaxf(acc[mi][kj][r], 0.f) * w2v;
        }
#pragma unroll
        for (int mi = 0; mi < 4; ++mi)
#pragma unroll
            for (int r = 0; r < 4; ++r) {
                float v = p[mi][r];
                v += __shfl_xor(v, 8);
                v += __shfl_xor(v, 4);
                v += __shfl_xor(v, 2);
                v += __shfl_xor(v, 1);
                p[mi][r] = v;
            }
        if (c == 0) {
#pragma unroll
            for (int mi = 0; mi < 4; ++mi)
                *(float4*)&psum[w][16 * mi + 4 * q] =
                    make_float4(p[mi][0], p[mi][1], p[mi][2], p[mi][3]);
        }
        __syncthreads();   // psum ready; all zh reads done
        if (t < 64) {
            float sd = 0.f;
            const float* urow = U + (m0 + t) * 8;
#pragma unroll
            for (int d = 0; d < 8; ++d) sd += urow[d] * ws[WS_YV + n * 8 + d];
            float pp = psum[0][t] + psum[1][t] + psum[2][t] + psum[3][t];
            ws[WS_SLACK + n * 2048 + m0 + t] = sd - cu2 - pp;
        }
    }
}

// ---------------------------------------------------------------------------
// k_lse: per-n stable logsumexp over m -> psi[n]
// ---------------------------------------------------------------------------
__global__ __launch_bounds__(256) void k_lse(const float* __restrict__ ws,
                                             float* __restrict__ out) {
    __shared__ float redmax[4];
    __shared__ float redsum[4];
    const int n = blockIdx.x;
    const int t = threadIdx.x;
    const float* s = ws + WS_SLACK + n * 2048;

    float vals[8];
    float mx = -3.4e38f;
#pragma unroll
    for (int i = 0; i < 8; ++i) {
        vals[i] = s[t + 256 * i];
        mx = fmaxf(mx, vals[i]);
    }
#pragma unroll
    for (int off = 32; off; off >>= 1) mx = fmaxf(mx, __shfl_xor(mx, off));
    if ((t & 63) == 0) redmax[t >> 6] = mx;
    __syncthreads();
    mx = fmaxf(fmaxf(redmax[0], redmax[1]), fmaxf(redmax[2], redmax[3]));

    float sum = 0.f;
#pragma unroll
    for (int i = 0; i < 8; ++i) sum += expf((vals[i] - mx) * (1.f / EPSF));
#pragma unroll
    for (int off = 32; off; off >>= 1) sum += __shfl_xor(sum, off);
    if ((t & 63) == 0) redsum[t >> 6] = sum;
    __syncthreads();
    if (t == 0) {
        float S = redsum[0] + redsum[1] + redsum[2] + redsum[3];
        out[n] = EPSF * logf(S * (1.f / 2048.f)) + mx;
    }
}

// ---------------------------------------------------------------------------
extern "C" void kernel_launch(void* const* d_in, const int* in_sizes, int n_in,
                              void* d_out, int out_size, void* d_ws, size_t ws_size,
                              hipStream_t stream) {
    const float* X    = (const float*)d_in[0];
    const float* Uu   = (const float*)d_in[1];
    const float* Yy   = (const float*)d_in[2];
    const float* Wt0  = (const float*)d_in[3];
    const float* bt0  = (const float*)d_in[4];
    const float* Wt1  = (const float*)d_in[5];
    const float* bt1  = (const float*)d_in[6];
    const float* Wyu0 = (const float*)d_in[7];
    const float* byu0 = (const float*)d_in[8];
    const float* Wy0  = (const float*)d_in[9];
    const float* Wu0  = (const float*)d_in[10];
    const float* b0   = (const float*)d_in[11];
    const float* Wzu1 = (const float*)d_in[12];
    const float* bzu1 = (const float*)d_in[13];
    const float* Wz1  = (const float*)d_in[14];
    const float* Wyu1 = (const float*)d_in[15];
    const float* byu1 = (const float*)d_in[16];
    const float* Wy1  = (const float*)d_in[17];
    const float* Wu1  = (const float*)d_in[18];
    const float* b1   = (const float*)d_in[19];
    const float* Wzu2 = (const float*)d_in[20];
    const float* bzu2 = (const float*)d_in[21];
    const float* Wz2  = (const float*)d_in[22];
    const float* Wyu2 = (const float*)d_in[23];
    const float* byu2 = (const float*)d_in[24];
    const float* Wy2  = (const float*)d_in[25];
    const float* Wu2  = (const float*)d_in[26];
    const float* b2   = (const float*)d_in[27];
    float* ws  = (float*)d_ws;
    float* out = (float*)d_out;

    k_prep<<<dim3(256), dim3(256), 0, stream>>>(Wz1, ws);
    k_lvlA<<<dim3(9),   dim3(256), 0, stream>>>(X, Wt0, bt0, Wu0, b0, Wyu0, byu0, ws);
    k_lvlB<<<dim3(13),  dim3(256), 0, stream>>>(Wt1, bt1, Wzu1, bzu1, Wu1, b1, Wyu1, byu1, ws);
    k_lvlC<<<dim3(5),   dim3(256), 0, stream>>>(Yy, Wzu2, bzu2, Wz2, Wyu2, byu2, Wy2, Wu2, b2, ws);
    k_main<<<dim3(16, 128), dim3(256), 0, stream>>>(Uu, Wy0, Wy1, ws);
    k_lse<<<dim3(128), dim3(256), 0, stream>>>(ws, out);
}